// Round 1
// 197.735 us; speedup vs baseline: 1.0017x; 1.0017x over previous
//
#include <hip/hip_runtime.h>

// GroupConv2D: NHWC, B=32, H=W=56, Cin=Cout=256, groups=8 (32 ch/group), 3x3 SAME.
// Implicit-GEMM per group: M/N swap-able 16x16 tiles, K=288 (9 taps x 32 ci).
// mfma_f32_16x16x32_bf16: one K-step == one (ky,kx) tap, 8 contiguous ci per lane.
//
// R3 changes vs R2 (71 us dispatch; 2.3 TB/s, MfmaUtil 8%, VALU 15%, Occ 35%,
// VGPR 64 -- latency-bound staging: ~1-2 loads in flight/wave):
//  1. staging loop split into issue-all-19-loads (branchless, clamped addr,
//     fully unrolled into regs, NO dependent ops between loads) then
//     convert+ds_write. ~19 float4 in flight/wave instead of ~1.5; uses the
//     free VGPR headroom (64 -> ~110, cap 128 at 4 blocks/CU).
//  2. MFMA operand swap (weights as A, pixels as B): D becomes [co][pixel],
//     reg r = 4 consecutive co -> epilogue is 14 dwordx4 stores/thread
//     instead of 56 scalar dword stores (+4x less address VALU).
// Target: ~40 us (traffic unchanged ~166 MB; concurrency fix, not traffic fix).

#define R_ 8                 // output rows per block
#define TPW 7                // 16-pixel tiles per wave (28 tiles / 4 waves)

typedef __bf16 bf16x8 __attribute__((ext_vector_type(8)));
typedef float floatx4 __attribute__((ext_vector_type(4)));
typedef unsigned short ushortx4 __attribute__((ext_vector_type(4)));

__device__ __forceinline__ unsigned short f2bf(float f) {
    unsigned int u = __builtin_bit_cast(unsigned int, f);
    u += 0x7fffu + ((u >> 16) & 1u);           // round-to-nearest-even
    return (unsigned short)(u >> 16);
}

// ---- prep: wgt fp32 [tap][ci][co256] -> ws bf16 [g][tap][co][ci]  (73728 elems)
__global__ __launch_bounds__(256)
void wprep(const float* __restrict__ wgt, unsigned short* __restrict__ wbf) {
    const int i = blockIdx.x * 256 + threadIdx.x;       // grid sized exactly
    const int co256 = i & 255;
    const int tmp   = i >> 8;
    const int ci    = tmp & 31;
    const int kk    = tmp >> 5;                          // 0..8
    const int g  = co256 >> 5;
    const int co = co256 & 31;
    wbf[((g * 9 + kk) * 32 + co) * 32 + ci] = f2bf(wgt[i]);
}

__global__ __launch_bounds__(256, 4)
void gconv_mfma(const float* __restrict__ in, const unsigned short* __restrict__ wbf,
                const float* __restrict__ bias, float* __restrict__ out) {
    const int rt = blockIdx.x;      // 0..6 row-strip
    const int g  = blockIdx.y;      // 0..7 group
    const int b  = blockIdx.z;      // 0..31 batch
    const int y0 = rt * R_;

    __shared__ unsigned short lds_in[10 * 58 * 32];   // [row][col][ci] bf16, 37120 B

    const int tid = threadIdx.x;

    // ---- stage input halo tile: rows y0-1..y0+8 (10), cols -1..56 (58), 32 ci
    // chunk = 4 consecutive ci (16B load -> 8B LDS write), 4640 chunks, 19/thread.
    // Phase 1: issue ALL loads back-to-back, fire-and-forget into registers.
    // Branchless: invalid chunks load in[0] (cached, harmless), zeroed in phase 2.
    float4 v[19];
#pragma unroll
    for (int i = 0; i < 19; ++i) {
        const int c   = tid + (i << 8);
        const int row = c / 464;            // 58*8
        const int rem = c - row * 464;
        const int gy  = y0 - 1 + row;
        const int gx  = (rem >> 3) - 1;
        const bool ok = (c < 4640) & ((unsigned)gy < 56u) & ((unsigned)gx < 56u);
        const int gidx = ok ? ((((b * 56 + gy) * 56 + gx) << 8) + (g << 5) + ((rem & 7) << 2))
                            : 0;
        v[i] = *reinterpret_cast<const float4*>(&in[gidx]);
    }
    // Phase 2: convert + LDS write (vmcnt waits amortize across 19 in-flight loads)
#pragma unroll
    for (int i = 0; i < 19; ++i) {
        const int c = tid + (i << 8);
        if (c < 4640) {
            const int row = c / 464;
            const int rem = c - row * 464;
            const int gy  = y0 - 1 + row;
            const int gx  = (rem >> 3) - 1;
            float4 w = v[i];
            if (!(((unsigned)gy < 56u) & ((unsigned)gx < 56u)))
                w = make_float4(0.f, 0.f, 0.f, 0.f);
            ushortx4 p;
            p.x = f2bf(w.x); p.y = f2bf(w.y); p.z = f2bf(w.z); p.w = f2bf(w.w);
            *reinterpret_cast<ushortx4*>(
                &lds_in[(row * 58 + (rem >> 3)) * 32 + ((rem & 7) << 2)]) = p;
        }
    }

    __syncthreads();

    const int wv   = tid >> 6;
    const int lane = tid & 63;
    const int lc   = lane & 15;    // weights-A: m-index (co); pixels-B: n (pixel)
    const int quad = lane >> 4;

    // per-lane B (pixel) base address (ushort units) for each of 7 pixel tiles
    int lane_base[TPW];
#pragma unroll
    for (int t = 0; t < TPW; ++t) {
        const int p  = (wv * TPW + t) * 16 + lc;     // output pixel 0..447 in strip
        const int yl = p / 56;
        const int xl = p - yl * 56;
        lane_base[t] = (yl * 58 + xl) * 32 + (quad << 3);
    }

    // weight fragment base in ws: [g][kk][co][ci] bf16; lane (lc,quad) -> co=lc, ci=quad*8
    const unsigned short* wq = &wbf[(g * 9 * 32) * 32 + (quad << 3)];

    floatx4 acc[TPW][2];
#pragma unroll
    for (int t = 0; t < TPW; ++t) {
        acc[t][0] = (floatx4)(0.f);
        acc[t][1] = (floatx4)(0.f);
    }

    // prefetch tap 0's weight fragments (L2-hot)
    bf16x8 b0 = *reinterpret_cast<const bf16x8*>(&wq[(0 * 32 + lc) * 32]);
    bf16x8 b1 = *reinterpret_cast<const bf16x8*>(&wq[(0 * 32 + 16 + lc) * 32]);

#pragma unroll
    for (int kk = 0; kk < 9; ++kk) {
        const int ky = kk / 3, kx = kk % 3;
        const int koff = (ky * 58 + kx) * 32;        // wave-uniform tap offset
        bf16x8 nb0 = b0, nb1 = b1;
        if (kk < 8) {   // prefetch next tap while MFMAs run
            nb0 = *reinterpret_cast<const bf16x8*>(&wq[((kk + 1) * 32 + lc) * 32]);
            nb1 = *reinterpret_cast<const bf16x8*>(&wq[((kk + 1) * 32 + 16 + lc) * 32]);
        }
#pragma unroll
        for (int t = 0; t < TPW; ++t) {
            const bf16x8 a = *reinterpret_cast<const bf16x8*>(&lds_in[lane_base[t] + koff]);
            // A=weights (m=co), B=pixels (n=pixel) -> D[row=co][col=pixel]
            acc[t][0] = __builtin_amdgcn_mfma_f32_16x16x32_bf16(b0, a, acc[t][0], 0, 0, 0);
            acc[t][1] = __builtin_amdgcn_mfma_f32_16x16x32_bf16(b1, a, acc[t][1], 0, 0, 0);
        }
        b0 = nb0; b1 = nb1;
    }

    // ---- epilogue: D row=quad*4+r = co, col=lc = pixel-in-tile.
    // reg r = 4 consecutive co -> one dwordx4 per acc half. Lanes l,l+16,l+32,l+48
    // cover co 0..15 of the same pixel -> contiguous 64B segments per instr.
    const float4 bv0 = *reinterpret_cast<const float4*>(&bias[(g << 5) + (quad << 2)]);
    const float4 bv1 = *reinterpret_cast<const float4*>(&bias[(g << 5) + 16 + (quad << 2)]);
    const int obase = (((b * 56 + y0) * 56) << 8) + (g << 5) + (quad << 2);
#pragma unroll
    for (int t = 0; t < TPW; ++t) {
        const int p = (wv * TPW + t) * 16 + lc;
        const int y = p / 56;
        const int x = p - y * 56;
        float* o = &out[obase + ((y * 56 + x) << 8)];
        float4 s0, s1;
        s0.x = acc[t][0][0] + bv0.x; s0.y = acc[t][0][1] + bv0.y;
        s0.z = acc[t][0][2] + bv0.z; s0.w = acc[t][0][3] + bv0.w;
        s1.x = acc[t][1][0] + bv1.x; s1.y = acc[t][1][1] + bv1.y;
        s1.z = acc[t][1][2] + bv1.z; s1.w = acc[t][1][3] + bv1.w;
        *reinterpret_cast<float4*>(o)      = s0;
        *reinterpret_cast<float4*>(o + 16) = s1;
    }
}

// ---------------- fallback (round-1 kernel, known correct) if ws too small ----
__global__ __launch_bounds__(256, 2)
void gconv_mfma_ldsw(const float* __restrict__ in, const float* __restrict__ wgt,
                     const float* __restrict__ bias, float* __restrict__ out) {
    const int rt = blockIdx.x, g = blockIdx.y, b = blockIdx.z;
    const int y0 = rt * R_;
    __shared__ unsigned short lds_in[10 * 58 * 32];
    __shared__ unsigned short lds_w[9 * 32 * 32];
    const int tid = threadIdx.x;
    for (int i = tid; i < 9 * 32 * 32; i += 256) {
        const int co = i & 31, ci = (i >> 5) & 31, kk = i >> 10;
        lds_w[(kk * 32 + co) * 32 + ci] = f2bf(wgt[(kk * 32 + ci) * 256 + g * 32 + co]);
    }
    for (int c = tid; c < 10 * 58 * 8; c += 256) {
        const int row = c / 464, rem = c - row * 464, col = rem >> 3, q = rem & 7;
        const int gy = y0 - 1 + row, gx = col - 1;
        float4 v = make_float4(0.f, 0.f, 0.f, 0.f);
        if ((unsigned)gy < 56u && (unsigned)gx < 56u)
            v = *reinterpret_cast<const float4*>(&in[(((b * 56 + gy) * 56 + gx) * 256) + g * 32 + q * 4]);
        ushortx4 p;
        p.x = f2bf(v.x); p.y = f2bf(v.y); p.z = f2bf(v.z); p.w = f2bf(v.w);
        *reinterpret_cast<ushortx4*>(&lds_in[(row * 58 + col) * 32 + q * 4]) = p;
    }
    __syncthreads();
    const int wv = tid >> 6, lane = tid & 63, lc = lane & 15, quad = lane >> 4;
    int lane_base[TPW];
#pragma unroll
    for (int t = 0; t < TPW; ++t) {
        const int p = (wv * TPW + t) * 16 + lc;
        const int yl = p / 56, xl = p - yl * 56;
        lane_base[t] = (yl * 58 + xl) * 32 + quad * 8;
    }
    floatx4 acc[TPW][2];
#pragma unroll
    for (int t = 0; t < TPW; ++t) { acc[t][0] = (floatx4)(0.f); acc[t][1] = (floatx4)(0.f); }
#pragma unroll
    for (int kk = 0; kk < 9; ++kk) {
        const int ky = kk / 3, kx = kk % 3;
        const int koff = (ky * 58 + kx) * 32;
        const bf16x8 bf0 = *reinterpret_cast<const bf16x8*>(&lds_w[(kk * 32 + lc) * 32 + quad * 8]);
        const bf16x8 bf1 = *reinterpret_cast<const bf16x8*>(&lds_w[(kk * 32 + 16 + lc) * 32 + quad * 8]);
#pragma unroll
        for (int t = 0; t < TPW; ++t) {
            const bf16x8 a = *reinterpret_cast<const bf16x8*>(&lds_in[lane_base[t] + koff]);
            acc[t][0] = __builtin_amdgcn_mfma_f32_16x16x32_bf16(a, bf0, acc[t][0], 0, 0, 0);
            acc[t][1] = __builtin_amdgcn_mfma_f32_16x16x32_bf16(a, bf1, acc[t][1], 0, 0, 0);
        }
    }
    const float bv0 = bias[g * 32 + lc], bv1 = bias[g * 32 + 16 + lc];
#pragma unroll
    for (int t = 0; t < TPW; ++t)
#pragma unroll
        for (int r = 0; r < 4; ++r) {
            const int p = (wv * TPW + t) * 16 + quad * 4 + r;
            const int y = p / 56, x = p - y * 56;
            float* o = &out[(((b * 56) + y0 + y) * 56 + x) * 256 + g * 32];
            o[lc] = acc[t][0][r] + bv0;
            o[16 + lc] = acc[t][1][r] + bv1;
        }
}

extern "C" void kernel_launch(void* const* d_in, const int* in_sizes, int n_in,
                              void* d_out, int out_size, void* d_ws, size_t ws_size,
                              hipStream_t stream) {
    const float* in   = (const float*)d_in[0];
    const float* wgt  = (const float*)d_in[1];
    const float* bias = (const float*)d_in[2];
    float* out        = (float*)d_out;
    dim3 grid(7, 8, 32);   // (row-strips, groups, batch)

    if (ws_size >= (size_t)(8 * 9 * 32 * 32 * sizeof(unsigned short))) {
        unsigned short* wbf = (unsigned short*)d_ws;
        wprep<<<dim3(288, 1, 1), dim3(256, 1, 1), 0, stream>>>(wgt, wbf);
        gconv_mfma<<<grid, dim3(256, 1, 1), 0, stream>>>(in, wbf, bias, out);
    } else {
        gconv_mfma_ldsw<<<grid, dim3(256, 1, 1), 0, stream>>>(in, wgt, bias, out);
    }
}